// Round 6
// baseline (566.553 us; speedup 1.0000x reference)
//
#include <hip/hip_runtime.h>
#include <cstdint>

#define DM   1024
#define NH   16
#define DK   64
#define DFF  2688
#define SEQ  2048
#define BB   2
#define MTOT (BB*SEQ)   // 4096

typedef __attribute__((ext_vector_type(8))) short short8;
typedef __attribute__((ext_vector_type(4))) float f32x4;

typedef const __attribute__((address_space(1))) void* gaddr_t;
typedef __attribute__((address_space(3))) void* laddr_t;
#define GLOAD_LDS16(g, l) __builtin_amdgcn_global_load_lds((gaddr_t)(g), (laddr_t)(l), 16, 0, 0)
#define MFMA16(a, b, c) __builtin_amdgcn_mfma_f32_16x16x32_bf16((a), (b), (c), 0, 0, 0)
#define WAIT_LDS() __builtin_amdgcn_s_waitcnt(0xc07f)   // lgkmcnt(0) only, vmcnt stays in flight

__device__ __forceinline__ float bf2f(unsigned short u) {
    union { unsigned int i; float f; } v; v.i = ((unsigned int)u) << 16; return v.f;
}
__device__ __forceinline__ unsigned short f2bf(float f) {
    union { float f; unsigned int i; } v; v.f = f;
    unsigned int r = v.i + 0x7fffu + ((v.i >> 16) & 1u);
    return (unsigned short)(r >> 16);
}
__device__ __forceinline__ unsigned long long pack4bf(float a, float b, float c, float d) {
    return (unsigned long long)f2bf(a) | ((unsigned long long)f2bf(b) << 16)
         | ((unsigned long long)f2bf(c) << 32) | ((unsigned long long)f2bf(d) << 48);
}

// ---------------- fused fp32->bf16 weight convert (all 7 weights, 1 launch) ----
__global__ __launch_bounds__(256)
void prep_k(const float* __restrict__ q_w, const float* __restrict__ k_w,
            const float* __restrict__ v_w, const float* __restrict__ o_w,
            const float* __restrict__ w1_w, const float* __restrict__ w3_w,
            const float* __restrict__ w2_w,
            unsigned short* __restrict__ Wqkv, unsigned short* __restrict__ Wo,
            unsigned short* __restrict__ W13, unsigned short* __restrict__ W2) {
    const int blk = blockIdx.x;
    const float* src; unsigned short* dst; int cols, rmul, roff, i;
    if (blk < 4096) {
        const int rr = blk >> 10;
        i = (blk & 1023) * 256 + threadIdx.x;
        cols = 1024; rmul = 1;
        if (rr == 0)      { src = q_w; dst = Wqkv; roff = 0; }
        else if (rr == 1) { src = k_w; dst = Wqkv; roff = 1024; }
        else if (rr == 2) { src = v_w; dst = Wqkv; roff = 2048; }
        else              { src = o_w; dst = Wo;   roff = 0; }
    } else if (blk < 6784) {
        i = (blk - 4096) * 256 + threadIdx.x; src = w1_w; dst = W13; cols = 1024; rmul = 2; roff = 0;
    } else if (blk < 9472) {
        i = (blk - 6784) * 256 + threadIdx.x; src = w3_w; dst = W13; cols = 1024; rmul = 2; roff = 1;
    } else {
        i = (blk - 9472) * 256 + threadIdx.x; src = w2_w; dst = W2;  cols = 2688; rmul = 1; roff = 0;
    }
    const int e = i * 4;
    const int r = e / cols, c = e - r * cols;
    const float4 v = *(const float4*)(src + e);
    ushort4 o;
    o.x = f2bf(v.x); o.y = f2bf(v.y); o.z = f2bf(v.z); o.w = f2bf(v.w);
    *(ushort4*)(dst + (size_t)(r * rmul + roff) * cols + c) = o;
}

// ---------------- RMSNorm (row of 1024), fp32 in -> bf16 out -------------------
__global__ __launch_bounds__(256)
void rmsnorm_k(const float* __restrict__ x, const float* __restrict__ w,
               unsigned short* __restrict__ out) {
    const int row = blockIdx.x;
    const int tid = threadIdx.x;
    const float4 v = ((const float4*)(x + (size_t)row * DM))[tid];
    float ss = v.x * v.x + v.y * v.y + v.z * v.z + v.w * v.w;
#pragma unroll
    for (int off = 32; off > 0; off >>= 1) ss += __shfl_down(ss, off, 64);
    __shared__ float sred[4];
    const int wave = tid >> 6, lane = tid & 63;
    if (lane == 0) sred[wave] = ss;
    __syncthreads();
    const float tot = sred[0] + sred[1] + sred[2] + sred[3];
    const float rinv = rsqrtf(tot * (1.0f / DM) + 1e-5f);
    const float4 wv = ((const float4*)w)[tid];
    ushort4 o;
    o.x = f2bf(v.x * wv.x * rinv);
    o.y = f2bf(v.y * wv.y * rinv);
    o.z = f2bf(v.z * wv.z * rinv);
    o.w = f2bf(v.w * wv.w * rinv);
    ((ushort4*)(out + (size_t)row * DM))[tid] = o;
}

// ---------------- big-tile GEMM: 256x128 block, BK=32, 2-barrier ---------------
// Wave tile 128x64, acc[8][4] (128 AGPR). Intensity 85 FLOP/staged-byte flips
// the kernel from L2-delivery-bound (128x128 = 64 F/B ~= exactly L2 rate) to
// compute-dominated. Transposed acc (MFMA(bg,af)) -> vectorized epilogue.
template <int EPI>
__global__ __launch_bounds__(256)
void gemm_big(const unsigned short* __restrict__ A,
              const unsigned short* __restrict__ B,
              unsigned short* __restrict__ Cb,
              float* __restrict__ Cf,
              const float* __restrict__ R,
              int N, int K) {
    __shared__ unsigned short As[8192];   // [k8 0..3][256 rows][8]
    __shared__ unsigned short Bs[4096];   // [k8 0..3][128 rows][8]
    const int tid = threadIdx.x;
    const int wave = tid >> 6, lane = tid & 63;
    const int l15 = lane & 15, quad = lane >> 4;
    const int m0 = blockIdx.y * 256, n0 = blockIdx.x * 128;
    const int wr = (wave >> 1) * 128, wc = (wave & 1) * 64;

    const f32x4 z4 = {0.f, 0.f, 0.f, 0.f};
    f32x4 acc[8][4];
#pragma unroll
    for (int i = 0; i < 8; i++)
#pragma unroll
        for (int j = 0; j < 4; j++) acc[i][j] = z4;

    // staging: A 1024 segs (4/thread), B 512 segs (2/thread); LDS dest is
    // wave-uniform base + lane*16B (global_load_lds constraint)
    const unsigned short* ap[4];
    int al[4];
#pragma unroll
    for (int i = 0; i < 4; i++) {
        const int s = i * 256 + tid;
        ap[i] = A + (size_t)(m0 + (s & 255)) * K + (s >> 8) * 8;
        al[i] = (i * 256 + wave * 64) * 8;
    }
    const unsigned short* bp[2];
    int bl[2];
#pragma unroll
    for (int i = 0; i < 2; i++) {
        const int s = i * 256 + tid;
        bp[i] = B + (size_t)(n0 + (s & 127)) * K + (s >> 7) * 8;
        bl[i] = (i * 256 + wave * 64) * 8;
    }

    const int nk = K >> 5;
    for (int kc = 0; kc < nk; kc++) {
        __syncthreads();                       // prev chunk's ds_reads done (WAR)
#pragma unroll
        for (int i = 0; i < 4; i++) { GLOAD_LDS16(ap[i], &As[al[i]]); ap[i] += 32; }
#pragma unroll
        for (int i = 0; i < 2; i++) { GLOAD_LDS16(bp[i], &Bs[bl[i]]); bp[i] += 32; }
        __syncthreads();                       // staging complete
        short8 bg[4];
#pragma unroll
        for (int j = 0; j < 4; j++)
            bg[j] = *(const short8*)(&Bs[(quad * 128 + wc + j * 16 + l15) * 8]);
#pragma unroll
        for (int h = 0; h < 2; h++) {
            short8 af[4];
#pragma unroll
            for (int t = 0; t < 4; t++)
                af[t] = *(const short8*)(&As[(quad * 256 + wr + h * 64 + t * 16 + l15) * 8]);
#pragma unroll
            for (int t = 0; t < 4; t++)
#pragma unroll
                for (int j = 0; j < 4; j++)
                    acc[h * 4 + t][j] = MFMA16(bg[j], af[t], acc[h * 4 + t][j]);
        }
    }

    // epilogue: lane holds row m0+wr+i*16+l15, cols n0+wc+j*16+quad*4 .. +3
#pragma unroll
    for (int i = 0; i < 8; i++) {
        const int r = m0 + wr + i * 16 + l15;
#pragma unroll
        for (int j = 0; j < 4; j++) {
            const int cc = n0 + wc + j * 16 + quad * 4;
            const size_t idx = (size_t)r * N + cc;
            if (EPI == 0) {
                *(unsigned long long*)(Cb + idx) =
                    pack4bf(acc[i][j][0], acc[i][j][1], acc[i][j][2], acc[i][j][3]);
            } else {
                const float4 rv = *(const float4*)(R + idx);
                float4 ov;
                ov.x = acc[i][j][0] + rv.x;
                ov.y = acc[i][j][1] + rv.y;
                ov.z = acc[i][j][2] + rv.z;
                ov.w = acc[i][j][3] + rv.w;
                *(float4*)(Cf + idx) = ov;
            }
        }
    }
}

// ---------------- thin-N GEMM: 128x64 block, BK=64 (for N=1024 cases) ----------
template <int EPI>
__global__ __launch_bounds__(256)
void gemm_thin(const unsigned short* __restrict__ A,
               const unsigned short* __restrict__ B,
               unsigned short* __restrict__ Cb,
               float* __restrict__ Cf,
               const float* __restrict__ R,
               int N, int K) {
    __shared__ unsigned short As[8192];        // [k8 0..7][128 rows][8]
    __shared__ unsigned short Bs[4096];        // [k8 0..7][64 rows][8]
    const int tid = threadIdx.x;
    const int wave = tid >> 6, lane = tid & 63;
    const int l15 = lane & 15, quad = lane >> 4;
    const int m0 = blockIdx.y * 128, n0 = blockIdx.x * 64;
    const int wr = (wave & 1) * 64, wc = (wave >> 1) * 32;

    const f32x4 z4 = {0.f, 0.f, 0.f, 0.f};
    f32x4 acc[4][2];
#pragma unroll
    for (int i = 0; i < 4; i++)
#pragma unroll
        for (int j = 0; j < 2; j++) acc[i][j] = z4;

    const unsigned short* ap[4];
    int al[4];
#pragma unroll
    for (int i = 0; i < 4; i++) {
        const int s = i * 256 + tid;
        ap[i] = A + (size_t)(m0 + (s & 127)) * K + (s >> 7) * 8;
        al[i] = (i * 256 + wave * 64) * 8;
    }
    const unsigned short* bp[2];
    int bl[2];
#pragma unroll
    for (int i = 0; i < 2; i++) {
        const int s = i * 256 + tid;
        bp[i] = B + (size_t)(n0 + (s & 63)) * K + (s >> 6) * 8;
        bl[i] = (i * 256 + wave * 64) * 8;
    }

    const int nk = K >> 6;
    for (int kc = 0; kc < nk; kc++) {
        __syncthreads();
#pragma unroll
        for (int i = 0; i < 4; i++) { GLOAD_LDS16(ap[i], &As[al[i]]); ap[i] += 64; }
#pragma unroll
        for (int i = 0; i < 2; i++) { GLOAD_LDS16(bp[i], &Bs[bl[i]]); bp[i] += 64; }
        __syncthreads();
#pragma unroll
        for (int h = 0; h < 2; h++) {
            short8 af[4], bg[2];
#pragma unroll
            for (int t = 0; t < 4; t++)
                af[t] = *(const short8*)(&As[((quad + 4 * h) * 128 + wr + t * 16 + l15) * 8]);
#pragma unroll
            for (int t = 0; t < 2; t++)
                bg[t] = *(const short8*)(&Bs[((quad + 4 * h) * 64 + wc + t * 16 + l15) * 8]);
#pragma unroll
            for (int i = 0; i < 4; i++)
#pragma unroll
                for (int j = 0; j < 2; j++)
                    acc[i][j] = MFMA16(bg[j], af[i], acc[i][j]);
        }
    }

#pragma unroll
    for (int i = 0; i < 4; i++) {
        const int r = m0 + wr + i * 16 + l15;
#pragma unroll
        for (int j = 0; j < 2; j++) {
            const int cc = n0 + wc + j * 16 + quad * 4;
            const size_t idx = (size_t)r * N + cc;
            if (EPI == 0) {
                *(unsigned long long*)(Cb + idx) =
                    pack4bf(acc[i][j][0], acc[i][j][1], acc[i][j][2], acc[i][j][3]);
            } else {
                const float4 rv = *(const float4*)(R + idx);
                float4 ov;
                ov.x = acc[i][j][0] + rv.x;
                ov.y = acc[i][j][1] + rv.y;
                ov.z = acc[i][j][2] + rv.z;
                ov.w = acc[i][j][3] + rv.w;
                *(float4*)(Cf + idx) = ov;
            }
        }
    }
}

// ---------------- RoPE cos/sin table: tab[s][0:32]=cos, [32:64]=sin ------------
__global__ void rope_tab_k(const int* __restrict__ pos, float* __restrict__ tab) {
    const int s = blockIdx.x, t = threadIdx.x;
    const int kk = t & 31;
    const float ang = (float)pos[s] * __expf(-0.28782313662f * (float)kk); // 10000^(-kk/32)
    tab[s * 64 + t] = (t < 32) ? cosf(ang) : sinf(ang);
}

// ---------------- RoPE: QKV[4096,3072] -> Qr/Kr [B,H,S,DK] (bf16) -------------
__global__ __launch_bounds__(256)
void rope_k(const unsigned short* __restrict__ qkv, const float* __restrict__ tab,
            unsigned short* __restrict__ Qr, unsigned short* __restrict__ Kr) {
    const int m = blockIdx.x;
    const int s = m & (SEQ - 1), b = m >> 11;
    const int tid = threadIdx.x;
#pragma unroll
    for (int i = 0; i < 2; i++) {
        const int pr = i * 256 + tid;
        const int h = pr >> 5, k = pr & 31;
        const float cs = tab[s * 64 + k];
        const float sn = tab[s * 64 + 32 + k];
        const size_t so = (size_t)m * 3072 + h * 64 + 2 * k;
        const size_t doff = ((size_t)(b * NH + h) * SEQ + s) * DK + 2 * k;
        const unsigned int q2 = *(const unsigned int*)(qkv + so);
        float xe = bf2f((unsigned short)(q2 & 0xffffu));
        float xo = bf2f((unsigned short)(q2 >> 16));
        *(unsigned int*)(Qr + doff) =
            (unsigned int)f2bf(xe * cs - xo * sn) | ((unsigned int)f2bf(xe * sn + xo * cs) << 16);
        const unsigned int k2 = *(const unsigned int*)(qkv + so + 1024);
        xe = bf2f((unsigned short)(k2 & 0xffffu));
        xo = bf2f((unsigned short)(k2 >> 16));
        *(unsigned int*)(Kr + doff) =
            (unsigned int)f2bf(xe * cs - xo * sn) | ((unsigned int)f2bf(xe * sn + xo * cs) << 16);
    }
}

// ---------------- V transpose: QKV V-section -> Vt [B,H,DK,S] ------------------
__global__ __launch_bounds__(256)
void vtrans_k(const unsigned short* __restrict__ qkv, unsigned short* __restrict__ Vt) {
    __shared__ unsigned short tile[64 * 72];
    const int bh = blockIdx.y;
    const int b = bh >> 4, h = bh & 15;
    const int s0 = blockIdx.x * 64;
    const int tid = threadIdx.x;
#pragma unroll
    for (int i = 0; i < 2; i++) {
        const int idx = i * 256 + tid;
        const int sl = idx >> 3, d8 = (idx & 7) * 8;
        const uint4 v = *(const uint4*)(qkv + (size_t)(b * SEQ + s0 + sl) * 3072 + 2048 + h * 64 + d8);
        *(uint4*)(tile + sl * 72 + d8) = v;
    }
    __syncthreads();
#pragma unroll
    for (int i = 0; i < 2; i++) {
        const int idx = i * 256 + tid;
        const int d = idx >> 3, s8 = (idx & 7) * 8;
        unsigned short tmp[8] __attribute__((aligned(16)));
#pragma unroll
        for (int j = 0; j < 8; j++) tmp[j] = tile[(s8 + j) * 72 + d];
        *(uint4*)(Vt + ((size_t)bh * DK + d) * SEQ + s0 + s8) = *(const uint4*)tmp;
    }
}

// ---------------- softmax tile update (max-free, per-lane partial li) ----------
template <bool MASK>
__device__ __forceinline__ void softmax_tile(f32x4 st[4], float& li, unsigned short* Pw,
                                             int l15, int quad, int j0, int myq) {
    float lsum = 0.f;
#pragma unroll
    for (int t = 0; t < 4; t++) {
#pragma unroll
        for (int r = 0; r < 4; r++) {
            float v = st[t][r] * 0.125f;
            if (MASK) {
                const int key = j0 + t * 16 + quad * 4 + r;
                if (key > myq) v = -1e30f;
            }
            const float p = __expf(v);
            st[t][r] = p;
            lsum += p;
        }
        *(unsigned long long*)(Pw + l15 * 72 + t * 16 + quad * 4) =
            pack4bf(st[t][0], st[t][1], st[t][2], st[t][3]);
    }
    li += lsum;
}

// ---------------- Flash attention v3: block-staged K/V, paired q-tiles ---------
__global__ __launch_bounds__(256, 2)
void attn_k(const unsigned short* __restrict__ Qr, const unsigned short* __restrict__ Kr,
            const unsigned short* __restrict__ Vt, unsigned short* __restrict__ ctx) {
    __shared__ unsigned short KVl[2][8192];   // [buf][K 4096 shorts | V 4096 shorts]
    __shared__ unsigned short Pl[4 * 2 * 1152];
    const int tid = threadIdx.x;
    const int wave = tid >> 6, lane = tid & 63;
    const int l15 = lane & 15, quad = lane >> 4;
    const int bh = blockIdx.y, b = bh >> 4, h = bh & 15;
    const int g = blockIdx.x;
    const int qtA = g * 4 + wave, qtB = 127 - qtA;
    const int q0A = qtA * 16, q0B = qtB * 16;
    const int countA = g + 1, countB = 32 - g;   // block-uniform
    const unsigned short* Kb = Kr + (size_t)bh * SEQ * DK;
    const unsigned short* Vb = Vt + (size_t)bh * DK * SEQ;

    const unsigned short* QbA = Qr + ((size_t)bh * SEQ + q0A) * DK;
    const unsigned short* QbB = Qr + ((size_t)bh * SEQ + q0B) * DK;
    const short8 qfA0 = *(const short8*)(QbA + l15 * DK + quad * 8);
    const short8 qfA1 = *(const short8*)(QbA + l15 * DK + 32 + quad * 8);
    const short8 qfB0 = *(const short8*)(QbB + l15 * DK + quad * 8);
    const short8 qfB1 = *(const short8*)(QbB + l15 * DK + 32 + quad * 8);

    const int slot0 = wave * 128 + lane, slot1 = slot0 + 64;
    const int ck0 = slot0 >> 3, s0 = slot0 & 7;
    const int ck1 = slot1 >> 3, s1 = slot1 & 7;
    const unsigned short* kp0 = Kb + ck0 * 64 + (s0 ^ (ck0 & 7)) * 8;
    const unsigned short* kp1 = Kb + ck1 * 64 + (s1 ^ (ck1 & 7)) * 8;
    const unsigned short* vp0 = Vb + ck0 * 2048 + (s0 ^ (ck0 & 7)) * 8;
    const unsigned short* vp1 = Vb + ck1 * 2048 + (s1 ^ (ck1 & 7)) * 8;
    const int kb0 = wave * 1024, kb1 = kb0 + 512;

    unsigned short* PA = Pl + (wave * 2 + 0) * 1152;
    unsigned short* PB = Pl + (wave * 2 + 1) * 1152;

    const f32x4 z4 = {0.f, 0.f, 0.f, 0.f};
    f32x4 oA[4], oB[4];
#pragma unroll
    for (int d = 0; d < 4; d++) { oA[d] = z4; oB[d] = z4; }
    float liA = 0.f, liB = 0.f;
    const int myqA = q0A + l15, myqB = q0B + l15;
    const int xr = l15 & 7;

    GLOAD_LDS16(kp0, &KVl[0][kb0]);
    GLOAD_LDS16(kp1, &KVl[0][kb1]);
    GLOAD_LDS16(vp0, &KVl[0][4096 + kb0]);
    GLOAD_LDS16(vp1, &KVl[0][4096 + kb1]);
    kp0 += 4096; kp1 += 4096; vp0 += 64; vp1 += 64;

    for (int j = 0; j < countB; ++j) {
        const int bf = j & 1;
        const unsigned short* Kl = KVl[bf];
        const unsigned short* Vl = KVl[bf] + 4096;
        __syncthreads();
        if (j + 1 < countB) {
            GLOAD_LDS16(kp0, &KVl[bf ^ 1][kb0]);
            GLOAD_LDS16(kp1, &KVl[bf ^ 1][kb1]);
            GLOAD_LDS16(vp0, &KVl[bf ^ 1][4096 + kb0]);
            GLOAD_LDS16(vp1, &KVl[bf ^ 1][4096 + kb1]);
            kp0 += 4096; kp1 += 4096; vp0 += 64; vp1 += 64;
        }
        const int j0 = j * 64;
        short8 kf[4][2];
#pragma unroll
        for (int t = 0; t < 4; t++) {
            const unsigned short* kr = Kl + (t * 16 + l15) * 64;
            kf[t][0] = *(const short8*)(kr + (quad ^ xr) * 8);
            kf[t][1] = *(const short8*)(kr + ((4 + quad) ^ xr) * 8);
        }
        f32x4 stB[4];
#pragma unroll
        for (int t = 0; t < 4; t++)
            stB[t] = MFMA16(kf[t][1], qfB1, MFMA16(kf[t][0], qfB0, z4));
        const bool doA = (j < countA);
        if (doA) {
            f32x4 stA[4];
#pragma unroll
            for (int t = 0; t < 4; t++)
                stA[t] = MFMA16(kf[t][1], qfA1, MFMA16(kf[t][0], qfA0, z4));
            if (j == countA - 1) softmax_tile<true >(stA, liA, PA, l15, quad, j0, myqA);
            else                 softmax_tile<false>(stA, liA, PA, l15, quad, j0, myqA);
        }
        if (j == countB - 1) softmax_tile<true >(stB, liB, PB, l15, quad, j0, myqB);
        else                 softmax_tile<false>(stB, liB, PB, l15, quad, j0, myqB);
        WAIT_LDS();
        short8 vf[4][2];
#pragma unroll
        for (int dt = 0; dt < 4; dt++) {
            const unsigned short* vr = Vl + (dt * 16 + l15) * 64;
            vf[dt][0] = *(const short8*)(vr + (quad ^ xr) * 8);
            vf[dt][1] = *(const short8*)(vr + ((4 + quad) ^ xr) * 8);
        }
        {
            const short8 pfB0 = *(const short8*)(PB + l15 * 72 + quad * 8);
            const short8 pfB1 = *(const short8*)(PB + l15 * 72 + 32 + quad * 8);
#pragma unroll
            for (int dt = 0; dt < 4; dt++)
                oB[dt] = MFMA16(vf[dt][1], pfB1, MFMA16(vf[dt][0], pfB0, oB[dt]));
        }
        if (doA) {
            const short8 pfA0 = *(const short8*)(PA + l15 * 72 + quad * 8);
            const short8 pfA1 = *(const short8*)(PA + l15 * 72 + 32 + quad * 8);
#pragma unroll
            for (int dt = 0; dt < 4; dt++)
                oA[dt] = MFMA16(vf[dt][1], pfA1, MFMA16(vf[dt][0], pfA0, oA[dt]));
        }
    }
    liA += __shfl_xor(liA, 16, 64); liA += __shfl_xor(liA, 32, 64);
    liB += __shfl_xor(liB, 16, 64); liB += __shfl_xor(liB, 32, 64);
    const float invA = 1.0f / liA, invB = 1.0f / liB;
#pragma unroll
    for (int dt = 0; dt < 4; dt++) {
        *(unsigned long long*)(PA + l15 * 72 + dt * 16 + quad * 4) =
            pack4bf(oA[dt][0] * invA, oA[dt][1] * invA, oA[dt][2] * invA, oA[dt][3] * invA);
        *(unsigned long long*)(PB + l15 * 72 + dt * 16 + quad * 4) =
            pack4bf(oB[dt][0] * invB, oB[dt][1] * invB, oB[dt][2] * invB, oB[dt][3] * invB);
    }
    WAIT_LDS();
    const int row = lane >> 2, seg = (lane & 3) * 8;
#pragma unroll
    for (int p = 0; p < 2; p++) {
        const int cs = seg + p * 32;
        const uint4 va = *(const uint4*)(PA + row * 72 + cs);
        *(uint4*)(ctx + ((size_t)b * SEQ + q0A + row) * DM + h * DK + cs) = va;
        const uint4 vb = *(const uint4*)(PB + row * 72 + cs);
        *(uint4*)(ctx + ((size_t)b * SEQ + q0B + row) * DM + h * DK + cs) = vb;
    }
}

// ---------------- SwiGLU: act[m,i] = silu(gu[m,2i]) * gu[m,2i+1] ---------------
__global__ __launch_bounds__(256)
void silu_k(const unsigned short* __restrict__ gu, unsigned short* __restrict__ act, int npairs) {
    const int i = blockIdx.x * 256 + threadIdx.x;
    const int p0 = i * 4;
    if (p0 >= npairs) return;
    unsigned short in[8] __attribute__((aligned(16)));
    *(uint4*)in = *(const uint4*)(gu + (size_t)p0 * 2);
    unsigned short ov[8] __attribute__((aligned(8)));
#pragma unroll
    for (int j = 0; j < 4; j++) {
        const float g = bf2f(in[2 * j]);
        const float u = bf2f(in[2 * j + 1]);
        ov[j] = f2bf(g * u / (1.f + __expf(-g)));
    }
    *(ushort4*)(act + p0) = *(const ushort4*)ov;
}

extern "C" void kernel_launch(void* const* d_in, const int* in_sizes, int n_in,
                              void* d_out, int out_size, void* d_ws, size_t ws_size,
                              hipStream_t stream) {
    const float* x     = (const float*)d_in[0];
    const float* ln1_w = (const float*)d_in[1];
    const float* q_w   = (const float*)d_in[2];
    const float* k_w   = (const float*)d_in[3];
    const float* v_w   = (const float*)d_in[4];
    const float* o_w   = (const float*)d_in[5];
    const float* ln2_w = (const float*)d_in[6];
    const float* w1_w  = (const float*)d_in[7];
    const float* w3_w  = (const float*)d_in[8];
    const float* w2_w  = (const float*)d_in[9];
    const int*   tpos  = (const int*)d_in[10];
    float* out = (float*)d_out;
    char* ws = (char*)d_ws;

    unsigned short* Wqkv = (unsigned short*)(ws + 0);
    unsigned short* Wo   = (unsigned short*)(ws + 6291456);
    unsigned short* W13  = (unsigned short*)(ws + 8388608);
    unsigned short* W2   = (unsigned short*)(ws + 19398656);
    float*          X1   = (float*)(ws + 24903680);           // also rope tab (dead then)
    float*          ROPT = (float*)(ws + 24903680);
    char* base = ws + 41680896;
    unsigned short* H    = (unsigned short*)(base);
    unsigned short* QKV  = (unsigned short*)(base + 8388608);
    unsigned short* QR   = (unsigned short*)(base + 33554432);
    unsigned short* KR   = (unsigned short*)(base + 41943040);
    unsigned short* VT   = (unsigned short*)(base + 50331648);
    unsigned short* CTX  = (unsigned short*)(base);
    unsigned short* H2   = (unsigned short*)(base + 8388608);
    unsigned short* GU   = (unsigned short*)(base + 16777216);
    unsigned short* ACT  = (unsigned short*)(base + 60817408);

    prep_k<<<12160, 256, 0, stream>>>(q_w, k_w, v_w, o_w, w1_w, w3_w, w2_w,
                                      Wqkv, Wo, W13, W2);
    rope_tab_k<<<2048, 64, 0, stream>>>(tpos, ROPT);

    rmsnorm_k<<<4096, 256, 0, stream>>>(x, ln1_w, H);
    gemm_big<0><<<dim3(24, 16), 256, 0, stream>>>(H, Wqkv, QKV, nullptr, nullptr, 3072, 1024);
    rope_k<<<4096, 256, 0, stream>>>(QKV, ROPT, QR, KR);
    vtrans_k<<<dim3(32, 32), 256, 0, stream>>>(QKV, VT);
    attn_k<<<dim3(16, 32), 256, 0, stream>>>(QR, KR, VT, CTX);
    gemm_thin<1><<<dim3(16, 32), 256, 0, stream>>>(CTX, Wo, nullptr, X1, x, 1024, 1024);
    rmsnorm_k<<<4096, 256, 0, stream>>>(X1, ln2_w, H2);
    gemm_big<0><<<dim3(42, 16), 256, 0, stream>>>(H2, W13, GU, nullptr, nullptr, 5376, 1024);
    silu_k<<<10752, 256, 0, stream>>>(GU, ACT, 11010048);
    gemm_thin<1><<<dim3(16, 32), 256, 0, stream>>>(ACT, W2, nullptr, out, X1, 1024, 2688);
}

// Round 7
// 497.655 us; speedup vs baseline: 1.1384x; 1.1384x over previous
//
#include <hip/hip_runtime.h>
#include <cstdint>

#define DM   1024
#define NH   16
#define DK   64
#define DFF  2688
#define SEQ  2048
#define BB   2
#define MTOT (BB*SEQ)   // 4096

typedef __attribute__((ext_vector_type(8))) short short8;
typedef __attribute__((ext_vector_type(4))) float f32x4;

typedef const __attribute__((address_space(1))) void* gaddr_t;
typedef __attribute__((address_space(3))) void* laddr_t;
#define GLOAD_LDS16(g, l) __builtin_amdgcn_global_load_lds((gaddr_t)(g), (laddr_t)(l), 16, 0, 0)
#define MFMA16(a, b, c) __builtin_amdgcn_mfma_f32_16x16x32_bf16((a), (b), (c), 0, 0, 0)
#define WAIT_LDS() __builtin_amdgcn_s_waitcnt(0xc07f)   // lgkmcnt(0) only, vmcnt stays in flight

__device__ __forceinline__ float bf2f(unsigned short u) {
    union { unsigned int i; float f; } v; v.i = ((unsigned int)u) << 16; return v.f;
}
__device__ __forceinline__ unsigned short f2bf(float f) {
    union { float f; unsigned int i; } v; v.f = f;
    unsigned int r = v.i + 0x7fffu + ((v.i >> 16) & 1u);
    return (unsigned short)(r >> 16);
}
__device__ __forceinline__ unsigned long long pack4bf(float a, float b, float c, float d) {
    return (unsigned long long)f2bf(a) | ((unsigned long long)f2bf(b) << 16)
         | ((unsigned long long)f2bf(c) << 32) | ((unsigned long long)f2bf(d) << 48);
}

// ---------------- fused fp32->bf16 weight convert (all 7 weights, 1 launch) ----
__global__ __launch_bounds__(256)
void prep_k(const float* __restrict__ q_w, const float* __restrict__ k_w,
            const float* __restrict__ v_w, const float* __restrict__ o_w,
            const float* __restrict__ w1_w, const float* __restrict__ w3_w,
            const float* __restrict__ w2_w,
            unsigned short* __restrict__ Wqkv, unsigned short* __restrict__ Wo,
            unsigned short* __restrict__ W13, unsigned short* __restrict__ W2) {
    const int blk = blockIdx.x;
    const float* src; unsigned short* dst; int cols, rmul, roff, i;
    if (blk < 4096) {
        const int rr = blk >> 10;
        i = (blk & 1023) * 256 + threadIdx.x;
        cols = 1024; rmul = 1;
        if (rr == 0)      { src = q_w; dst = Wqkv; roff = 0; }
        else if (rr == 1) { src = k_w; dst = Wqkv; roff = 1024; }
        else if (rr == 2) { src = v_w; dst = Wqkv; roff = 2048; }
        else              { src = o_w; dst = Wo;   roff = 0; }
    } else if (blk < 6784) {
        i = (blk - 4096) * 256 + threadIdx.x; src = w1_w; dst = W13; cols = 1024; rmul = 2; roff = 0;
    } else if (blk < 9472) {
        i = (blk - 6784) * 256 + threadIdx.x; src = w3_w; dst = W13; cols = 1024; rmul = 2; roff = 1;
    } else {
        i = (blk - 9472) * 256 + threadIdx.x; src = w2_w; dst = W2;  cols = 2688; rmul = 1; roff = 0;
    }
    const int e = i * 4;
    const int r = e / cols, c = e - r * cols;
    const float4 v = *(const float4*)(src + e);
    ushort4 o;
    o.x = f2bf(v.x); o.y = f2bf(v.y); o.z = f2bf(v.z); o.w = f2bf(v.w);
    *(ushort4*)(dst + (size_t)(r * rmul + roff) * cols + c) = o;
}

// ---------------- RMSNorm (row of 1024), fp32 in -> bf16 out -------------------
__global__ __launch_bounds__(256)
void rmsnorm_k(const float* __restrict__ x, const float* __restrict__ w,
               unsigned short* __restrict__ out) {
    const int row = blockIdx.x;
    const int tid = threadIdx.x;
    const float4 v = ((const float4*)(x + (size_t)row * DM))[tid];
    float ss = v.x * v.x + v.y * v.y + v.z * v.z + v.w * v.w;
#pragma unroll
    for (int off = 32; off > 0; off >>= 1) ss += __shfl_down(ss, off, 64);
    __shared__ float sred[4];
    const int wave = tid >> 6, lane = tid & 63;
    if (lane == 0) sred[wave] = ss;
    __syncthreads();
    const float tot = sred[0] + sred[1] + sred[2] + sred[3];
    const float rinv = rsqrtf(tot * (1.0f / DM) + 1e-5f);
    const float4 wv = ((const float4*)w)[tid];
    ushort4 o;
    o.x = f2bf(v.x * wv.x * rinv);
    o.y = f2bf(v.y * wv.y * rinv);
    o.z = f2bf(v.z * wv.z * rinv);
    o.w = f2bf(v.w * wv.w * rinv);
    ((ushort4*)(out + (size_t)row * DM))[tid] = o;
}

// ---------------- GEMM: 128x64 block, BK=64, 16 waves/CU occupancy -------------
// Wave tile 64x32, acc[4][2] = 32 AGPR; total regs engineered <= 128 so the
// pow2 register-allocation step (m69) gives 4 blocks/CU = 16 waves/CU — 2x the
// wave concurrency of the 128x128 config (the GEMMs are latency-bound: ~10
// B/cyc/CU delivery << L2 rate, 2 waves/SIMD can't cover ~900-cyc misses).
// __launch_bounds__(256,4): 2nd arg = min waves/EU = blocks/CU for 256-blocks.
template <int EPI>
__global__ __launch_bounds__(256, 4)
void gemm64(const unsigned short* __restrict__ A,
            const unsigned short* __restrict__ B,
            unsigned short* __restrict__ Cb,
            float* __restrict__ Cf,
            const float* __restrict__ R,
            int N, int K) {
    __shared__ unsigned short As[8192];        // [k8 0..7][128 rows][8]
    __shared__ unsigned short Bs[4096];        // [k8 0..7][64 rows][8]
    const int tid = threadIdx.x;
    const int wave = tid >> 6, lane = tid & 63;
    const int l15 = lane & 15, quad = lane >> 4;
    const int m0 = blockIdx.y * 128, n0 = blockIdx.x * 64;
    const int wr = (wave & 1) * 64, wc = (wave >> 1) * 32;

    const f32x4 z4 = {0.f, 0.f, 0.f, 0.f};
    f32x4 acc[4][2];
#pragma unroll
    for (int i = 0; i < 4; i++)
#pragma unroll
        for (int j = 0; j < 2; j++) acc[i][j] = z4;

    // staging: A 1024 segs (4/thread), B 512 segs (2/thread)
    const unsigned short* ap[4];
    int al[4];
#pragma unroll
    for (int i = 0; i < 4; i++) {
        const int s = i * 256 + tid;
        ap[i] = A + (size_t)(m0 + (s & 127)) * K + (s >> 7) * 8;
        al[i] = (i * 256 + wave * 64) * 8;     // wave-uniform LDS base
    }
    const unsigned short* bp[2];
    int bl[2];
#pragma unroll
    for (int i = 0; i < 2; i++) {
        const int s = i * 256 + tid;
        bp[i] = B + (size_t)(n0 + (s & 63)) * K + (s >> 6) * 8;
        bl[i] = (i * 256 + wave * 64) * 8;
    }

    const int nk = K >> 6;
    for (int kc = 0; kc < nk; kc++) {
        __syncthreads();                       // prev chunk's ds_reads done (WAR)
#pragma unroll
        for (int i = 0; i < 4; i++) { GLOAD_LDS16(ap[i], &As[al[i]]); ap[i] += 64; }
#pragma unroll
        for (int i = 0; i < 2; i++) { GLOAD_LDS16(bp[i], &Bs[bl[i]]); bp[i] += 64; }
        __syncthreads();                       // staging complete
#pragma unroll
        for (int h = 0; h < 2; h++) {
            short8 af[4], bg[2];
#pragma unroll
            for (int t = 0; t < 4; t++)
                af[t] = *(const short8*)(&As[((quad + 4 * h) * 128 + wr + t * 16 + l15) * 8]);
#pragma unroll
            for (int t = 0; t < 2; t++)
                bg[t] = *(const short8*)(&Bs[((quad + 4 * h) * 64 + wc + t * 16 + l15) * 8]);
#pragma unroll
            for (int i = 0; i < 4; i++)
#pragma unroll
                for (int j = 0; j < 2; j++)
                    acc[i][j] = MFMA16(bg[j], af[i], acc[i][j]);   // transposed acc
        }
    }

    // epilogue: lane holds row m0+wr+i*16+l15, cols n0+wc+j*16+quad*4 .. +3
#pragma unroll
    for (int i = 0; i < 4; i++) {
        const int r = m0 + wr + i * 16 + l15;
#pragma unroll
        for (int j = 0; j < 2; j++) {
            const int cc = n0 + wc + j * 16 + quad * 4;
            const size_t idx = (size_t)r * N + cc;
            if (EPI == 0) {
                *(unsigned long long*)(Cb + idx) =
                    pack4bf(acc[i][j][0], acc[i][j][1], acc[i][j][2], acc[i][j][3]);
            } else {
                const float4 rv = *(const float4*)(R + idx);
                float4 ov;
                ov.x = acc[i][j][0] + rv.x;
                ov.y = acc[i][j][1] + rv.y;
                ov.z = acc[i][j][2] + rv.z;
                ov.w = acc[i][j][3] + rv.w;
                *(float4*)(Cf + idx) = ov;
            }
        }
    }
}

// ---------------- RoPE cos/sin table: tab[s][0:32]=cos, [32:64]=sin ------------
__global__ void rope_tab_k(const int* __restrict__ pos, float* __restrict__ tab) {
    const int s = blockIdx.x, t = threadIdx.x;
    const int kk = t & 31;
    const float ang = (float)pos[s] * __expf(-0.28782313662f * (float)kk); // 10000^(-kk/32)
    tab[s * 64 + t] = (t < 32) ? cosf(ang) : sinf(ang);
}

// ---------------- RoPE: QKV[4096,3072] -> Qr/Kr [B,H,S,DK] (bf16) -------------
__global__ __launch_bounds__(256)
void rope_k(const unsigned short* __restrict__ qkv, const float* __restrict__ tab,
            unsigned short* __restrict__ Qr, unsigned short* __restrict__ Kr) {
    const int m = blockIdx.x;
    const int s = m & (SEQ - 1), b = m >> 11;
    const int tid = threadIdx.x;
#pragma unroll
    for (int i = 0; i < 2; i++) {
        const int pr = i * 256 + tid;
        const int h = pr >> 5, k = pr & 31;
        const float cs = tab[s * 64 + k];
        const float sn = tab[s * 64 + 32 + k];
        const size_t so = (size_t)m * 3072 + h * 64 + 2 * k;
        const size_t doff = ((size_t)(b * NH + h) * SEQ + s) * DK + 2 * k;
        const unsigned int q2 = *(const unsigned int*)(qkv + so);
        float xe = bf2f((unsigned short)(q2 & 0xffffu));
        float xo = bf2f((unsigned short)(q2 >> 16));
        *(unsigned int*)(Qr + doff) =
            (unsigned int)f2bf(xe * cs - xo * sn) | ((unsigned int)f2bf(xe * sn + xo * cs) << 16);
        const unsigned int k2 = *(const unsigned int*)(qkv + so + 1024);
        xe = bf2f((unsigned short)(k2 & 0xffffu));
        xo = bf2f((unsigned short)(k2 >> 16));
        *(unsigned int*)(Kr + doff) =
            (unsigned int)f2bf(xe * cs - xo * sn) | ((unsigned int)f2bf(xe * sn + xo * cs) << 16);
    }
}

// ---------------- V transpose: QKV V-section -> Vt [B,H,DK,S] ------------------
__global__ __launch_bounds__(256)
void vtrans_k(const unsigned short* __restrict__ qkv, unsigned short* __restrict__ Vt) {
    __shared__ unsigned short tile[64 * 72];
    const int bh = blockIdx.y;
    const int b = bh >> 4, h = bh & 15;
    const int s0 = blockIdx.x * 64;
    const int tid = threadIdx.x;
#pragma unroll
    for (int i = 0; i < 2; i++) {
        const int idx = i * 256 + tid;
        const int sl = idx >> 3, d8 = (idx & 7) * 8;
        const uint4 v = *(const uint4*)(qkv + (size_t)(b * SEQ + s0 + sl) * 3072 + 2048 + h * 64 + d8);
        *(uint4*)(tile + sl * 72 + d8) = v;
    }
    __syncthreads();
#pragma unroll
    for (int i = 0; i < 2; i++) {
        const int idx = i * 256 + tid;
        const int d = idx >> 3, s8 = (idx & 7) * 8;
        unsigned short tmp[8] __attribute__((aligned(16)));
#pragma unroll
        for (int j = 0; j < 8; j++) tmp[j] = tile[(s8 + j) * 72 + d];
        *(uint4*)(Vt + ((size_t)bh * DK + d) * SEQ + s0 + s8) = *(const uint4*)tmp;
    }
}

// ---------------- softmax tile update (max-free, per-lane partial li) ----------
template <bool MASK>
__device__ __forceinline__ void softmax_tile(f32x4 st[4], float& li, unsigned short* Pw,
                                             int l15, int quad, int j0, int myq) {
    float lsum = 0.f;
#pragma unroll
    for (int t = 0; t < 4; t++) {
#pragma unroll
        for (int r = 0; r < 4; r++) {
            float v = st[t][r] * 0.125f;
            if (MASK) {
                const int key = j0 + t * 16 + quad * 4 + r;
                if (key > myq) v = -1e30f;
            }
            const float p = __expf(v);
            st[t][r] = p;
            lsum += p;
        }
        *(unsigned long long*)(Pw + l15 * 72 + t * 16 + quad * 4) =
            pack4bf(st[t][0], st[t][1], st[t][2], st[t][3]);
    }
    li += lsum;
}

// ---------------- Flash attention v3: block-staged K/V, paired q-tiles ---------
__global__ __launch_bounds__(256, 2)
void attn_k(const unsigned short* __restrict__ Qr, const unsigned short* __restrict__ Kr,
            const unsigned short* __restrict__ Vt, unsigned short* __restrict__ ctx) {
    __shared__ unsigned short KVl[2][8192];   // [buf][K 4096 shorts | V 4096 shorts]
    __shared__ unsigned short Pl[4 * 2 * 1152];
    const int tid = threadIdx.x;
    const int wave = tid >> 6, lane = tid & 63;
    const int l15 = lane & 15, quad = lane >> 4;
    const int bh = blockIdx.y, b = bh >> 4, h = bh & 15;
    const int g = blockIdx.x;
    const int qtA = g * 4 + wave, qtB = 127 - qtA;
    const int q0A = qtA * 16, q0B = qtB * 16;
    const int countA = g + 1, countB = 32 - g;   // block-uniform
    const unsigned short* Kb = Kr + (size_t)bh * SEQ * DK;
    const unsigned short* Vb = Vt + (size_t)bh * DK * SEQ;

    const unsigned short* QbA = Qr + ((size_t)bh * SEQ + q0A) * DK;
    const unsigned short* QbB = Qr + ((size_t)bh * SEQ + q0B) * DK;
    const short8 qfA0 = *(const short8*)(QbA + l15 * DK + quad * 8);
    const short8 qfA1 = *(const short8*)(QbA + l15 * DK + 32 + quad * 8);
    const short8 qfB0 = *(const short8*)(QbB + l15 * DK + quad * 8);
    const short8 qfB1 = *(const short8*)(QbB + l15 * DK + 32 + quad * 8);

    const int slot0 = wave * 128 + lane, slot1 = slot0 + 64;
    const int ck0 = slot0 >> 3, s0 = slot0 & 7;
    const int ck1 = slot1 >> 3, s1 = slot1 & 7;
    const unsigned short* kp0 = Kb + ck0 * 64 + (s0 ^ (ck0 & 7)) * 8;
    const unsigned short* kp1 = Kb + ck1 * 64 + (s1 ^ (ck1 & 7)) * 8;
    const unsigned short* vp0 = Vb + ck0 * 2048 + (s0 ^ (ck0 & 7)) * 8;
    const unsigned short* vp1 = Vb + ck1 * 2048 + (s1 ^ (ck1 & 7)) * 8;
    const int kb0 = wave * 1024, kb1 = kb0 + 512;

    unsigned short* PA = Pl + (wave * 2 + 0) * 1152;
    unsigned short* PB = Pl + (wave * 2 + 1) * 1152;

    const f32x4 z4 = {0.f, 0.f, 0.f, 0.f};
    f32x4 oA[4], oB[4];
#pragma unroll
    for (int d = 0; d < 4; d++) { oA[d] = z4; oB[d] = z4; }
    float liA = 0.f, liB = 0.f;
    const int myqA = q0A + l15, myqB = q0B + l15;
    const int xr = l15 & 7;

    GLOAD_LDS16(kp0, &KVl[0][kb0]);
    GLOAD_LDS16(kp1, &KVl[0][kb1]);
    GLOAD_LDS16(vp0, &KVl[0][4096 + kb0]);
    GLOAD_LDS16(vp1, &KVl[0][4096 + kb1]);
    kp0 += 4096; kp1 += 4096; vp0 += 64; vp1 += 64;

    for (int j = 0; j < countB; ++j) {
        const int bf = j & 1;
        const unsigned short* Kl = KVl[bf];
        const unsigned short* Vl = KVl[bf] + 4096;
        __syncthreads();
        if (j + 1 < countB) {
            GLOAD_LDS16(kp0, &KVl[bf ^ 1][kb0]);
            GLOAD_LDS16(kp1, &KVl[bf ^ 1][kb1]);
            GLOAD_LDS16(vp0, &KVl[bf ^ 1][4096 + kb0]);
            GLOAD_LDS16(vp1, &KVl[bf ^ 1][4096 + kb1]);
            kp0 += 4096; kp1 += 4096; vp0 += 64; vp1 += 64;
        }
        const int j0 = j * 64;
        short8 kf[4][2];
#pragma unroll
        for (int t = 0; t < 4; t++) {
            const unsigned short* kr = Kl + (t * 16 + l15) * 64;
            kf[t][0] = *(const short8*)(kr + (quad ^ xr) * 8);
            kf[t][1] = *(const short8*)(kr + ((4 + quad) ^ xr) * 8);
        }
        f32x4 stB[4];
#pragma unroll
        for (int t = 0; t < 4; t++)
            stB[t] = MFMA16(kf[t][1], qfB1, MFMA16(kf[t][0], qfB0, z4));
        const bool doA = (j < countA);
        if (doA) {
            f32x4 stA[4];
#pragma unroll
            for (int t = 0; t < 4; t++)
                stA[t] = MFMA16(kf[t][1], qfA1, MFMA16(kf[t][0], qfA0, z4));
            if (j == countA - 1) softmax_tile<true >(stA, liA, PA, l15, quad, j0, myqA);
            else                 softmax_tile<false>(stA, liA, PA, l15, quad, j0, myqA);
        }
        if (j == countB - 1) softmax_tile<true >(stB, liB, PB, l15, quad, j0, myqB);
        else                 softmax_tile<false>(stB, liB, PB, l15, quad, j0, myqB);
        WAIT_LDS();
        short8 vf[4][2];
#pragma unroll
        for (int dt = 0; dt < 4; dt++) {
            const unsigned short* vr = Vl + (dt * 16 + l15) * 64;
            vf[dt][0] = *(const short8*)(vr + (quad ^ xr) * 8);
            vf[dt][1] = *(const short8*)(vr + ((4 + quad) ^ xr) * 8);
        }
        {
            const short8 pfB0 = *(const short8*)(PB + l15 * 72 + quad * 8);
            const short8 pfB1 = *(const short8*)(PB + l15 * 72 + 32 + quad * 8);
#pragma unroll
            for (int dt = 0; dt < 4; dt++)
                oB[dt] = MFMA16(vf[dt][1], pfB1, MFMA16(vf[dt][0], pfB0, oB[dt]));
        }
        if (doA) {
            const short8 pfA0 = *(const short8*)(PA + l15 * 72 + quad * 8);
            const short8 pfA1 = *(const short8*)(PA + l15 * 72 + 32 + quad * 8);
#pragma unroll
            for (int dt = 0; dt < 4; dt++)
                oA[dt] = MFMA16(vf[dt][1], pfA1, MFMA16(vf[dt][0], pfA0, oA[dt]));
        }
    }
    liA += __shfl_xor(liA, 16, 64); liA += __shfl_xor(liA, 32, 64);
    liB += __shfl_xor(liB, 16, 64); liB += __shfl_xor(liB, 32, 64);
    const float invA = 1.0f / liA, invB = 1.0f / liB;
#pragma unroll
    for (int dt = 0; dt < 4; dt++) {
        *(unsigned long long*)(PA + l15 * 72 + dt * 16 + quad * 4) =
            pack4bf(oA[dt][0] * invA, oA[dt][1] * invA, oA[dt][2] * invA, oA[dt][3] * invA);
        *(unsigned long long*)(PB + l15 * 72 + dt * 16 + quad * 4) =
            pack4bf(oB[dt][0] * invB, oB[dt][1] * invB, oB[dt][2] * invB, oB[dt][3] * invB);
    }
    WAIT_LDS();
    const int row = lane >> 2, seg = (lane & 3) * 8;
#pragma unroll
    for (int p = 0; p < 2; p++) {
        const int cs = seg + p * 32;
        const uint4 va = *(const uint4*)(PA + row * 72 + cs);
        *(uint4*)(ctx + ((size_t)b * SEQ + q0A + row) * DM + h * DK + cs) = va;
        const uint4 vb = *(const uint4*)(PB + row * 72 + cs);
        *(uint4*)(ctx + ((size_t)b * SEQ + q0B + row) * DM + h * DK + cs) = vb;
    }
}

// ---------------- SwiGLU: act[m,i] = silu(gu[m,2i]) * gu[m,2i+1] ---------------
__global__ __launch_bounds__(256)
void silu_k(const unsigned short* __restrict__ gu, unsigned short* __restrict__ act, int npairs) {
    const int i = blockIdx.x * 256 + threadIdx.x;
    const int p0 = i * 4;
    if (p0 >= npairs) return;
    unsigned short in[8] __attribute__((aligned(16)));
    *(uint4*)in = *(const uint4*)(gu + (size_t)p0 * 2);
    unsigned short ov[8] __attribute__((aligned(8)));
#pragma unroll
    for (int j = 0; j < 4; j++) {
        const float g = bf2f(in[2 * j]);
        const float u = bf2f(in[2 * j + 1]);
        ov[j] = f2bf(g * u / (1.f + __expf(-g)));
    }
    *(ushort4*)(act + p0) = *(const ushort4*)ov;
}

extern "C" void kernel_launch(void* const* d_in, const int* in_sizes, int n_in,
                              void* d_out, int out_size, void* d_ws, size_t ws_size,
                              hipStream_t stream) {
    const float* x     = (const float*)d_in[0];
    const float* ln1_w = (const float*)d_in[1];
    const float* q_w   = (const float*)d_in[2];
    const float* k_w   = (const float*)d_in[3];
    const float* v_w   = (const float*)d_in[4];
    const float* o_w   = (const float*)d_in[5];
    const float* ln2_w = (const float*)d_in[6];
    const float* w1_w  = (const float*)d_in[7];
    const float* w3_w  = (const float*)d_in[8];
    const float* w2_w  = (const float*)d_in[9];
    const int*   tpos  = (const int*)d_in[10];
    float* out = (float*)d_out;
    char* ws = (char*)d_ws;

    unsigned short* Wqkv = (unsigned short*)(ws + 0);
    unsigned short* Wo   = (unsigned short*)(ws + 6291456);
    unsigned short* W13  = (unsigned short*)(ws + 8388608);
    unsigned short* W2   = (unsigned short*)(ws + 19398656);
    float*          X1   = (float*)(ws + 24903680);           // also rope tab (dead then)
    float*          ROPT = (float*)(ws + 24903680);
    char* base = ws + 41680896;
    unsigned short* H    = (unsigned short*)(base);
    unsigned short* QKV  = (unsigned short*)(base + 8388608);
    unsigned short* QR   = (unsigned short*)(base + 33554432);
    unsigned short* KR   = (unsigned short*)(base + 41943040);
    unsigned short* VT   = (unsigned short*)(base + 50331648);
    unsigned short* CTX  = (unsigned short*)(base);
    unsigned short* H2   = (unsigned short*)(base + 8388608);
    unsigned short* GU   = (unsigned short*)(base + 16777216);
    unsigned short* ACT  = (unsigned short*)(base + 60817408);

    prep_k<<<12160, 256, 0, stream>>>(q_w, k_w, v_w, o_w, w1_w, w3_w, w2_w,
                                      Wqkv, Wo, W13, W2);
    rope_tab_k<<<2048, 64, 0, stream>>>(tpos, ROPT);

    rmsnorm_k<<<4096, 256, 0, stream>>>(x, ln1_w, H);
    gemm64<0><<<dim3(48, 32), 256, 0, stream>>>(H, Wqkv, QKV, nullptr, nullptr, 3072, 1024);
    rope_k<<<4096, 256, 0, stream>>>(QKV, ROPT, QR, KR);
    vtrans_k<<<dim3(32, 32), 256, 0, stream>>>(QKV, VT);
    attn_k<<<dim3(16, 32), 256, 0, stream>>>(QR, KR, VT, CTX);
    gemm64<1><<<dim3(16, 32), 256, 0, stream>>>(CTX, Wo, nullptr, X1, x, 1024, 1024);
    rmsnorm_k<<<4096, 256, 0, stream>>>(X1, ln2_w, H2);
    gemm64<0><<<dim3(84, 32), 256, 0, stream>>>(H2, W13, GU, nullptr, nullptr, 5376, 1024);
    silu_k<<<10752, 256, 0, stream>>>(GU, ACT, 11010048);
    gemm64<1><<<dim3(16, 32), 256, 0, stream>>>(ACT, W2, nullptr, out, X1, 1024, 2688);
}

// Round 8
// 425.247 us; speedup vs baseline: 1.3323x; 1.1703x over previous
//
#include <hip/hip_runtime.h>
#include <cstdint>

#define DM   1024
#define NH   16
#define DK   64
#define DFF  2688
#define SEQ  2048
#define BB   2
#define MTOT (BB*SEQ)   // 4096

typedef __attribute__((ext_vector_type(8))) short short8;
typedef __attribute__((ext_vector_type(4))) float f32x4;

typedef const __attribute__((address_space(1))) void* gaddr_t;
typedef __attribute__((address_space(3))) void* laddr_t;
#define GLOAD_LDS16(g, l) __builtin_amdgcn_global_load_lds((gaddr_t)(g), (laddr_t)(l), 16, 0, 0)
#define MFMA16(a, b, c) __builtin_amdgcn_mfma_f32_16x16x32_bf16((a), (b), (c), 0, 0, 0)
#define WAIT_LDS() __builtin_amdgcn_s_waitcnt(0xc07f)   // lgkmcnt(0) only

__device__ __forceinline__ float bf2f(unsigned short u) {
    union { unsigned int i; float f; } v; v.i = ((unsigned int)u) << 16; return v.f;
}
__device__ __forceinline__ unsigned short f2bf(float f) {
    union { float f; unsigned int i; } v; v.f = f;
    unsigned int r = v.i + 0x7fffu + ((v.i >> 16) & 1u);
    return (unsigned short)(r >> 16);
}
__device__ __forceinline__ unsigned long long pack4bf(float a, float b, float c, float d) {
    return (unsigned long long)f2bf(a) | ((unsigned long long)f2bf(b) << 16)
         | ((unsigned long long)f2bf(c) << 32) | ((unsigned long long)f2bf(d) << 48);
}

// ---------------- fused fp32->bf16 weight convert (all 7 weights, 1 launch) ----
__global__ __launch_bounds__(256)
void prep_k(const float* __restrict__ q_w, const float* __restrict__ k_w,
            const float* __restrict__ v_w, const float* __restrict__ o_w,
            const float* __restrict__ w1_w, const float* __restrict__ w3_w,
            const float* __restrict__ w2_w,
            unsigned short* __restrict__ Wqkv, unsigned short* __restrict__ Wo,
            unsigned short* __restrict__ W13, unsigned short* __restrict__ W2) {
    const int blk = blockIdx.x;
    const float* src; unsigned short* dst; int cols, rmul, roff, i;
    if (blk < 4096) {
        const int rr = blk >> 10;
        i = (blk & 1023) * 256 + threadIdx.x;
        cols = 1024; rmul = 1;
        if (rr == 0)      { src = q_w; dst = Wqkv; roff = 0; }
        else if (rr == 1) { src = k_w; dst = Wqkv; roff = 1024; }
        else if (rr == 2) { src = v_w; dst = Wqkv; roff = 2048; }
        else              { src = o_w; dst = Wo;   roff = 0; }
    } else if (blk < 6784) {
        i = (blk - 4096) * 256 + threadIdx.x; src = w1_w; dst = W13; cols = 1024; rmul = 2; roff = 0;
    } else if (blk < 9472) {
        i = (blk - 6784) * 256 + threadIdx.x; src = w3_w; dst = W13; cols = 1024; rmul = 2; roff = 1;
    } else {
        i = (blk - 9472) * 256 + threadIdx.x; src = w2_w; dst = W2;  cols = 2688; rmul = 1; roff = 0;
    }
    const int e = i * 4;
    const int r = e / cols, c = e - r * cols;
    const float4 v = *(const float4*)(src + e);
    ushort4 o;
    o.x = f2bf(v.x); o.y = f2bf(v.y); o.z = f2bf(v.z); o.w = f2bf(v.w);
    *(ushort4*)(dst + (size_t)(r * rmul + roff) * cols + c) = o;
}

// ---------------- RMSNorm (row of 1024), fp32 in -> bf16 out -------------------
__global__ __launch_bounds__(256)
void rmsnorm_k(const float* __restrict__ x, const float* __restrict__ w,
               unsigned short* __restrict__ out) {
    const int row = blockIdx.x;
    const int tid = threadIdx.x;
    const float4 v = ((const float4*)(x + (size_t)row * DM))[tid];
    float ss = v.x * v.x + v.y * v.y + v.z * v.z + v.w * v.w;
#pragma unroll
    for (int off = 32; off > 0; off >>= 1) ss += __shfl_down(ss, off, 64);
    __shared__ float sred[4];
    const int wave = tid >> 6, lane = tid & 63;
    if (lane == 0) sred[wave] = ss;
    __syncthreads();
    const float tot = sred[0] + sred[1] + sred[2] + sred[3];
    const float rinv = rsqrtf(tot * (1.0f / DM) + 1e-5f);
    const float4 wv = ((const float4*)w)[tid];
    ushort4 o;
    o.x = f2bf(v.x * wv.x * rinv);
    o.y = f2bf(v.y * wv.y * rinv);
    o.z = f2bf(v.z * wv.z * rinv);
    o.w = f2bf(v.w * wv.w * rinv);
    ((ushort4*)(out + (size_t)row * DM))[tid] = o;
}

// ---------------- rope table ---------------------------------------------------
__global__ void rope_tab_k(const int* __restrict__ pos, float* __restrict__ tab) {
    const int s = blockIdx.x, t = threadIdx.x;
    const int kk = t & 31;
    const float ang = (float)pos[s] * __expf(-0.28782313662f * (float)kk); // 10000^(-kk/32)
    tab[s * 64 + t] = (t < 32) ? cosf(ang) : sinf(ang);
}

// ======== 128x128 GEMM core (r3-proven: BK=32, 2-barrier, natural order) =======
// Transposed acc: lane holds row r=m0+wr+i*16+l15, cols cc..cc+3 (consecutive!)
// EPI 0: fused RoPE epilogue -> QR/KR/VT   EPI 1: fused SiLU -> ACT (N/2 cols)
template <int EPI>
__global__ __launch_bounds__(256)
void gemm128(const unsigned short* __restrict__ A,
             const unsigned short* __restrict__ B,
             unsigned short* __restrict__ O0,   // EPI0: QR   EPI1: ACT
             unsigned short* __restrict__ O1,   // EPI0: KR
             unsigned short* __restrict__ O2,   // EPI0: VT
             const float* __restrict__ ROPT,
             int N, int K) {
    __shared__ unsigned short As[4096];
    __shared__ unsigned short Bs[4096];
    const int tid = threadIdx.x;
    const int wave = tid >> 6, lane = tid & 63;
    const int l15 = lane & 15, quad = lane >> 4;
    const int m0 = blockIdx.y * 128, n0 = blockIdx.x * 128;
    const int wr = (wave >> 1) * 64, wc = (wave & 1) * 64;

    const f32x4 z4 = {0.f, 0.f, 0.f, 0.f};
    f32x4 acc[4][4];
#pragma unroll
    for (int i = 0; i < 4; i++)
#pragma unroll
        for (int j = 0; j < 4; j++) acc[i][j] = z4;

    const int c0 = tid, c1 = 256 + tid;
    const int k80 = c0 >> 7, mm0 = c0 & 127;
    const int k81 = c1 >> 7, mm1 = c1 & 127;
    const unsigned short* a0 = A + (size_t)(m0 + mm0) * K + k80 * 8;
    const unsigned short* a1 = A + (size_t)(m0 + mm1) * K + k81 * 8;
    const unsigned short* b0 = B + (size_t)(n0 + mm0) * K + k80 * 8;
    const unsigned short* b1 = B + (size_t)(n0 + mm1) * K + k81 * 8;
    unsigned short* lA0 = As + (wave * 64) * 8;
    unsigned short* lA1 = As + (256 + wave * 64) * 8;
    unsigned short* lB0 = Bs + (wave * 64) * 8;
    unsigned short* lB1 = Bs + (256 + wave * 64) * 8;

    for (int k0 = 0; k0 < K; k0 += 32) {
        __syncthreads();
        GLOAD_LDS16(a0 + k0, lA0);
        GLOAD_LDS16(a1 + k0, lA1);
        GLOAD_LDS16(b0 + k0, lB0);
        GLOAD_LDS16(b1 + k0, lB1);
        __syncthreads();
        short8 af[4], bg[4];
#pragma unroll
        for (int t = 0; t < 4; t++)
            af[t] = *(const short8*)(As + (quad * 128 + wr + t * 16 + l15) * 8);
#pragma unroll
        for (int t = 0; t < 4; t++)
            bg[t] = *(const short8*)(Bs + (quad * 128 + wc + t * 16 + l15) * 8);
#pragma unroll
        for (int i = 0; i < 4; i++)
#pragma unroll
            for (int j = 0; j < 4; j++)
                acc[i][j] = MFMA16(bg[j], af[i], acc[i][j]);   // transposed acc
    }

#pragma unroll
    for (int i = 0; i < 4; i++) {
        const int r = m0 + wr + i * 16 + l15;     // token row
        if (EPI == 0) {
            const int b = r >> 11, s = r & (SEQ - 1);
            const float* rt = ROPT + s * 64;
#pragma unroll
            for (int j = 0; j < 4; j++) {
                const int cb = n0 + wc + j * 16;          // uniform per j
                const int sec = cb >> 10;                  // 0=Q 1=K 2=V
                const int h = (cb & 1023) >> 6;
                const int cc0 = (cb & 63) + quad * 4;      // even
                const f32x4 a = acc[i][j];
                if (sec < 2) {
                    const int p0 = cc0 >> 1;
                    const float cA = rt[p0],     sA = rt[32 + p0];
                    const float cB = rt[p0 + 1], sB = rt[32 + p0 + 1];
                    const float e0 = a[0] * cA - a[1] * sA;
                    const float o0 = a[0] * sA + a[1] * cA;
                    const float e1 = a[2] * cB - a[3] * sB;
                    const float o1 = a[2] * sB + a[3] * cB;
                    unsigned short* dst = (sec == 0) ? O0 : O1;
                    *(unsigned long long*)(dst + ((size_t)(b * NH + h) * SEQ + s) * DK + cc0) =
                        pack4bf(e0, o0, e1, o1);
                } else {
                    unsigned short* dst = O2 + ((size_t)(b * NH + h) * DK) * SEQ + s;
#pragma unroll
                    for (int t = 0; t < 4; t++)
                        dst[(size_t)(cc0 + t) * SEQ] = f2bf(a[t]);
                }
            }
        } else {
#pragma unroll
            for (int j = 0; j < 4; j++) {
                const int cc = n0 + wc + j * 16 + quad * 4;   // even
                const f32x4 a = acc[i][j];
                const float s1 = a[0] * a[1] / (1.f + __expf(-a[0]));
                const float s2 = a[2] * a[3] / (1.f + __expf(-a[2]));
                *(unsigned int*)(O0 + (size_t)r * (DFF) + (cc >> 1)) =
                    (unsigned int)f2bf(s1) | ((unsigned int)f2bf(s2) << 16);
            }
        }
    }
}

// ---------------- thin-N GEMM: 128x64 block, BK=64, 4 blocks/CU ----------------
// EPI: fp32 out = acc + residual.  (proven r7 path for N=1024 GEMMs)
__global__ __launch_bounds__(256, 4)
void gemm_thin(const unsigned short* __restrict__ A,
               const unsigned short* __restrict__ B,
               float* __restrict__ Cf,
               const float* __restrict__ R,
               int N, int K) {
    __shared__ unsigned short As[8192];
    __shared__ unsigned short Bs[4096];
    const int tid = threadIdx.x;
    const int wave = tid >> 6, lane = tid & 63;
    const int l15 = lane & 15, quad = lane >> 4;
    const int m0 = blockIdx.y * 128, n0 = blockIdx.x * 64;
    const int wr = (wave & 1) * 64, wc = (wave >> 1) * 32;

    const f32x4 z4 = {0.f, 0.f, 0.f, 0.f};
    f32x4 acc[4][2];
#pragma unroll
    for (int i = 0; i < 4; i++)
#pragma unroll
        for (int j = 0; j < 2; j++) acc[i][j] = z4;

    const unsigned short* ap[4];
    int al[4];
#pragma unroll
    for (int i = 0; i < 4; i++) {
        const int s = i * 256 + tid;
        ap[i] = A + (size_t)(m0 + (s & 127)) * K + (s >> 7) * 8;
        al[i] = (i * 256 + wave * 64) * 8;
    }
    const unsigned short* bp[2];
    int bl[2];
#pragma unroll
    for (int i = 0; i < 2; i++) {
        const int s = i * 256 + tid;
        bp[i] = B + (size_t)(n0 + (s & 63)) * K + (s >> 6) * 8;
        bl[i] = (i * 256 + wave * 64) * 8;
    }

    const int nk = K >> 6;
    for (int kc = 0; kc < nk; kc++) {
        __syncthreads();
#pragma unroll
        for (int i = 0; i < 4; i++) { GLOAD_LDS16(ap[i], &As[al[i]]); ap[i] += 64; }
#pragma unroll
        for (int i = 0; i < 2; i++) { GLOAD_LDS16(bp[i], &Bs[bl[i]]); bp[i] += 64; }
        __syncthreads();
#pragma unroll
        for (int h = 0; h < 2; h++) {
            short8 af[4], bg[2];
#pragma unroll
            for (int t = 0; t < 4; t++)
                af[t] = *(const short8*)(&As[((quad + 4 * h) * 128 + wr + t * 16 + l15) * 8]);
#pragma unroll
            for (int t = 0; t < 2; t++)
                bg[t] = *(const short8*)(&Bs[((quad + 4 * h) * 64 + wc + t * 16 + l15) * 8]);
#pragma unroll
            for (int i = 0; i < 4; i++)
#pragma unroll
                for (int j = 0; j < 2; j++)
                    acc[i][j] = MFMA16(bg[j], af[i], acc[i][j]);
        }
    }

#pragma unroll
    for (int i = 0; i < 4; i++) {
        const int r = m0 + wr + i * 16 + l15;
#pragma unroll
        for (int j = 0; j < 2; j++) {
            const int cc = n0 + wc + j * 16 + quad * 4;
            const size_t idx = (size_t)r * N + cc;
            const float4 rv = *(const float4*)(R + idx);
            float4 ov;
            ov.x = acc[i][j][0] + rv.x;
            ov.y = acc[i][j][1] + rv.y;
            ov.z = acc[i][j][2] + rv.z;
            ov.w = acc[i][j][3] + rv.w;
            *(float4*)(Cf + idx) = ov;
        }
    }
}

// ---------------- softmax tile update (max-free, per-lane partial li) ----------
template <bool MASK>
__device__ __forceinline__ void softmax_tile(f32x4 st[4], float& li, unsigned short* Pw,
                                             int l15, int quad, int j0, int myq) {
    float lsum = 0.f;
#pragma unroll
    for (int t = 0; t < 4; t++) {
#pragma unroll
        for (int r = 0; r < 4; r++) {
            float v = st[t][r] * 0.125f;
            if (MASK) {
                const int key = j0 + t * 16 + quad * 4 + r;
                if (key > myq) v = -1e30f;
            }
            const float p = __expf(v);
            st[t][r] = p;
            lsum += p;
        }
        *(unsigned long long*)(Pw + l15 * 72 + t * 16 + quad * 4) =
            pack4bf(st[t][0], st[t][1], st[t][2], st[t][3]);
    }
    li += lsum;
}

// ---------------- Flash attention v3: block-staged K/V, paired q-tiles ---------
__global__ __launch_bounds__(256, 2)
void attn_k(const unsigned short* __restrict__ Qr, const unsigned short* __restrict__ Kr,
            const unsigned short* __restrict__ Vt, unsigned short* __restrict__ ctx) {
    __shared__ unsigned short KVl[2][8192];
    __shared__ unsigned short Pl[4 * 2 * 1152];
    const int tid = threadIdx.x;
    const int wave = tid >> 6, lane = tid & 63;
    const int l15 = lane & 15, quad = lane >> 4;
    const int bh = blockIdx.y, b = bh >> 4, h = bh & 15;
    const int g = blockIdx.x;
    const int qtA = g * 4 + wave, qtB = 127 - qtA;
    const int q0A = qtA * 16, q0B = qtB * 16;
    const int countA = g + 1, countB = 32 - g;
    const unsigned short* Kb = Kr + (size_t)bh * SEQ * DK;
    const unsigned short* Vb = Vt + (size_t)bh * DK * SEQ;

    const unsigned short* QbA = Qr + ((size_t)bh * SEQ + q0A) * DK;
    const unsigned short* QbB = Qr + ((size_t)bh * SEQ + q0B) * DK;
    const short8 qfA0 = *(const short8*)(QbA + l15 * DK + quad * 8);
    const short8 qfA1 = *(const short8*)(QbA + l15 * DK + 32 + quad * 8);
    const short8 qfB0 = *(const short8*)(QbB + l15 * DK + quad * 8);
    const short8 qfB1 = *(const short8*)(QbB + l15 * DK + 32 + quad * 8);

    const int slot0 = wave * 128 + lane, slot1 = slot0 + 64;
    const int ck0 = slot0 >> 3, s0 = slot0 & 7;
    const int ck1 = slot1 >> 3, s1 = slot1 & 7;
    const unsigned short* kp0 = Kb + ck0 * 64 + (s0 ^ (ck0 & 7)) * 8;
    const unsigned short* kp1 = Kb + ck1 * 64 + (s1 ^ (ck1 & 7)) * 8;
    const unsigned short* vp0 = Vb + ck0 * 2048 + (s0 ^ (ck0 & 7)) * 8;
    const unsigned short* vp1 = Vb + ck1 * 2048 + (s1 ^ (ck1 & 7)) * 8;
    const int kb0 = wave * 1024, kb1 = kb0 + 512;

    unsigned short* PA = Pl + (wave * 2 + 0) * 1152;
    unsigned short* PB = Pl + (wave * 2 + 1) * 1152;

    const f32x4 z4 = {0.f, 0.f, 0.f, 0.f};
    f32x4 oA[4], oB[4];
#pragma unroll
    for (int d = 0; d < 4; d++) { oA[d] = z4; oB[d] = z4; }
    float liA = 0.f, liB = 0.f;
    const int myqA = q0A + l15, myqB = q0B + l15;
    const int xr = l15 & 7;

    GLOAD_LDS16(kp0, &KVl[0][kb0]);
    GLOAD_LDS16(kp1, &KVl[0][kb1]);
    GLOAD_LDS16(vp0, &KVl[0][4096 + kb0]);
    GLOAD_LDS16(vp1, &KVl[0][4096 + kb1]);
    kp0 += 4096; kp1 += 4096; vp0 += 64; vp1 += 64;

    for (int j = 0; j < countB; ++j) {
        const int bf = j & 1;
        const unsigned short* Kl = KVl[bf];
        const unsigned short* Vl = KVl[bf] + 4096;
        __syncthreads();
        if (j + 1 < countB) {
            GLOAD_LDS16(kp0, &KVl[bf ^ 1][kb0]);
            GLOAD_LDS16(kp1, &KVl[bf ^ 1][kb1]);
            GLOAD_LDS16(vp0, &KVl[bf ^ 1][4096 + kb0]);
            GLOAD_LDS16(vp1, &KVl[bf ^ 1][4096 + kb1]);
            kp0 += 4096; kp1 += 4096; vp0 += 64; vp1 += 64;
        }
        const int j0 = j * 64;
        short8 kf[4][2];
#pragma unroll
        for (int t = 0; t < 4; t++) {
            const unsigned short* kr = Kl + (t * 16 + l15) * 64;
            kf[t][0] = *(const short8*)(kr + (quad ^ xr) * 8);
            kf[t][1] = *(const short8*)(kr + ((4 + quad) ^ xr) * 8);
        }
        f32x4 stB[4];
#pragma unroll
        for (int t = 0; t < 4; t++)
            stB[t] = MFMA16(kf[t][1], qfB1, MFMA16(kf[t][0], qfB0, z4));
        const bool doA = (j < countA);
        if (doA) {
            f32x4 stA[4];
#pragma unroll
            for (int t = 0; t < 4; t++)
                stA[t] = MFMA16(kf[t][1], qfA1, MFMA16(kf[t][0], qfA0, z4));
            if (j == countA - 1) softmax_tile<true >(stA, liA, PA, l15, quad, j0, myqA);
            else                 softmax_tile<false>(stA, liA, PA, l15, quad, j0, myqA);
        }
        if (j == countB - 1) softmax_tile<true >(stB, liB, PB, l15, quad, j0, myqB);
        else                 softmax_tile<false>(stB, liB, PB, l15, quad, j0, myqB);
        WAIT_LDS();
        short8 vf[4][2];
#pragma unroll
        for (int dt = 0; dt < 4; dt++) {
            const unsigned short* vr = Vl + (dt * 16 + l15) * 64;
            vf[dt][0] = *(const short8*)(vr + (quad ^ xr) * 8);
            vf[dt][1] = *(const short8*)(vr + ((4 + quad) ^ xr) * 8);
        }
        {
            const short8 pfB0 = *(const short8*)(PB + l15 * 72 + quad * 8);
            const short8 pfB1 = *(const short8*)(PB + l15 * 72 + 32 + quad * 8);
#pragma unroll
            for (int dt = 0; dt < 4; dt++)
                oB[dt] = MFMA16(vf[dt][1], pfB1, MFMA16(vf[dt][0], pfB0, oB[dt]));
        }
        if (doA) {
            const short8 pfA0 = *(const short8*)(PA + l15 * 72 + quad * 8);
            const short8 pfA1 = *(const short8*)(PA + l15 * 72 + 32 + quad * 8);
#pragma unroll
            for (int dt = 0; dt < 4; dt++)
                oA[dt] = MFMA16(vf[dt][1], pfA1, MFMA16(vf[dt][0], pfA0, oA[dt]));
        }
    }
    liA += __shfl_xor(liA, 16, 64); liA += __shfl_xor(liA, 32, 64);
    liB += __shfl_xor(liB, 16, 64); liB += __shfl_xor(liB, 32, 64);
    const float invA = 1.0f / liA, invB = 1.0f / liB;
#pragma unroll
    for (int dt = 0; dt < 4; dt++) {
        *(unsigned long long*)(PA + l15 * 72 + dt * 16 + quad * 4) =
            pack4bf(oA[dt][0] * invA, oA[dt][1] * invA, oA[dt][2] * invA, oA[dt][3] * invA);
        *(unsigned long long*)(PB + l15 * 72 + dt * 16 + quad * 4) =
            pack4bf(oB[dt][0] * invB, oB[dt][1] * invB, oB[dt][2] * invB, oB[dt][3] * invB);
    }
    WAIT_LDS();
    const int row = lane >> 2, seg = (lane & 3) * 8;
#pragma unroll
    for (int p = 0; p < 2; p++) {
        const int cs = seg + p * 32;
        const uint4 va = *(const uint4*)(PA + row * 72 + cs);
        *(uint4*)(ctx + ((size_t)b * SEQ + q0A + row) * DM + h * DK + cs) = va;
        const uint4 vb = *(const uint4*)(PB + row * 72 + cs);
        *(uint4*)(ctx + ((size_t)b * SEQ + q0B + row) * DM + h * DK + cs) = vb;
    }
}

extern "C" void kernel_launch(void* const* d_in, const int* in_sizes, int n_in,
                              void* d_out, int out_size, void* d_ws, size_t ws_size,
                              hipStream_t stream) {
    const float* x     = (const float*)d_in[0];
    const float* ln1_w = (const float*)d_in[1];
    const float* q_w   = (const float*)d_in[2];
    const float* k_w   = (const float*)d_in[3];
    const float* v_w   = (const float*)d_in[4];
    const float* o_w   = (const float*)d_in[5];
    const float* ln2_w = (const float*)d_in[6];
    const float* w1_w  = (const float*)d_in[7];
    const float* w3_w  = (const float*)d_in[8];
    const float* w2_w  = (const float*)d_in[9];
    const int*   tpos  = (const int*)d_in[10];
    float* out = (float*)d_out;
    char* ws = (char*)d_ws;

    unsigned short* Wqkv = (unsigned short*)(ws + 0);          // 6.29 MB
    unsigned short* Wo   = (unsigned short*)(ws + 6291456);    // 2.10 MB
    unsigned short* W13  = (unsigned short*)(ws + 8388608);    // 11.0 MB
    unsigned short* W2   = (unsigned short*)(ws + 19398656);   // 5.51 MB
    float*          X1   = (float*)(ws + 24903680);            // 16.78 MB (fp32)
    float*          ROPT = (float*)(ws + 24903680);            // alias: dead before X1 written
    char* base = ws + 41680896;
    unsigned short* H    = (unsigned short*)(base);             // 8.39 MB
    unsigned short* QR   = (unsigned short*)(base + 8388608);   // 8.39 MB
    unsigned short* KR   = (unsigned short*)(base + 16777216);  // 8.39 MB
    unsigned short* VT   = (unsigned short*)(base + 25165824);  // 8.39 MB
    unsigned short* CTX  = (unsigned short*)(base + 33554432);  // 8.39 MB
    unsigned short* H2   = (unsigned short*)(base);             // reuse H (dead after QKV)
    unsigned short* ACT  = (unsigned short*)(base + 41943040);  // 22.0 MB  (ends ~105.6 MB)

    prep_k<<<12160, 256, 0, stream>>>(q_w, k_w, v_w, o_w, w1_w, w3_w, w2_w,
                                      Wqkv, Wo, W13, W2);
    rope_tab_k<<<2048, 64, 0, stream>>>(tpos, ROPT);

    rmsnorm_k<<<4096, 256, 0, stream>>>(x, ln1_w, H);
    // QKV GEMM + fused RoPE + fused V-transpose
    gemm128<0><<<dim3(24, 32), 256, 0, stream>>>(H, Wqkv, QR, KR, VT, ROPT, 3072, 1024);
    attn_k<<<dim3(16, 32), 256, 0, stream>>>(QR, KR, VT, CTX);
    gemm_thin<<<dim3(16, 32), 256, 0, stream>>>(CTX, Wo, X1, x, 1024, 1024);
    rmsnorm_k<<<4096, 256, 0, stream>>>(X1, ln2_w, H2);
    // W13 GEMM + fused SwiGLU (w1/w3 row-interleaved)
    gemm128<1><<<dim3(42, 32), 256, 0, stream>>>(H2, W13, ACT, nullptr, nullptr, nullptr, 5376, 1024);
    gemm_thin<<<dim3(16, 32), 256, 0, stream>>>(ACT, W2, out, X1, 1024, 2688);
}